// Round 1
// baseline (4572.882 us; speedup 1.0000x reference)
//
#include <hip/hip_runtime.h>
#include <hip/hip_bf16.h>
#include <math.h>

// ---------------------------------------------------------------------------
// GeometricAugmentor forward, fp32 baseline.
// Key structural facts exploited:
//  * q,k of the QKV projection are DEAD (attention comes from pos embedding)
//    -> only compute v = xn @ Wqkv[:, 1024:1536].
//  * attention weights are identical across heads -> out = attn @ v directly.
//  * attn is computed ONCE and reused across all 4 layers.
// ---------------------------------------------------------------------------

#define B_    64
#define NTOK  196
#define CCH   3
#define PDIM  768
#define DIM   512
#define MLP   2048
#define MROWS (B_ * NTOK)      // 12544
#define IMGHW 224

static __device__ __forceinline__ float softplusf(float x) {
    return fmaxf(x, 0.0f) + log1pf(expf(-fabsf(x)));
}

// ------------------------- patchify: img -> (M,768) ------------------------
__global__ __launch_bounds__(256) void patchify_kernel(const float* __restrict__ img,
                                                       float* __restrict__ xp) {
    long idx = (long)blockIdx.x * blockDim.x + threadIdx.x;
    if (idx >= (long)MROWS * PDIM) return;
    int pd = (int)(idx % PDIM);
    long bn = idx / PDIM;
    int n = (int)(bn % NTOK);
    int b = (int)(bn / NTOK);
    int c = pd % 3;
    int p12 = pd / 3;
    int p1 = p12 >> 4, p2 = p12 & 15;
    int g1 = n / 14, g2 = n % 14;
    long src = (((long)b * CCH + c) * IMGHW + (g1 * 16 + p1)) * IMGHW + (g2 * 16 + p2);
    xp[idx] = img[src];
}

// ---------------------- unpatchify: (M,768) -> img -------------------------
__global__ __launch_bounds__(256) void unpatchify_kernel(const float* __restrict__ y,
                                                         float* __restrict__ out) {
    long idx = (long)blockIdx.x * blockDim.x + threadIdx.x;
    if (idx >= (long)B_ * CCH * IMGHW * IMGHW) return;
    int ww = (int)(idx % IMGHW);
    long r = idx / IMGHW;
    int hh = (int)(r % IMGHW);
    r /= IMGHW;
    int c = (int)(r % CCH);
    int b = (int)(r / CCH);
    int g1 = hh >> 4, p1 = hh & 15;
    int g2 = ww >> 4, p2 = ww & 15;
    int n = g1 * 14 + g2;
    int pd = (p1 * 16 + p2) * 3 + c;
    out[idx] = y[((long)b * NTOK + n) * PDIM + pd];
}

// -------- pos embedding: fused affine transform + random-Fourier ----------
__global__ __launch_bounds__(256) void pos_kernel(const float* __restrict__ Xc,
                                                  const float* __restrict__ Wfreq,
                                                  const float* __restrict__ A_noise,
                                                  const float* __restrict__ b_noise,
                                                  const float* __restrict__ A_mean,
                                                  const float* __restrict__ b_mean,
                                                  const float* __restrict__ A_std,
                                                  const float* __restrict__ b_std,
                                                  float* __restrict__ pos) {
    int bp = blockIdx.x;              // 0 .. 12543
    int b = bp / NTOK, p = bp % NTOK;
    int o = threadIdx.x;              // 0 .. 255
    float a00 = A_mean[0] + softplusf(A_std[0]) * A_noise[b * 4 + 0];
    float a01 = A_mean[1] + softplusf(A_std[1]) * A_noise[b * 4 + 1];
    float a10 = A_mean[2] + softplusf(A_std[2]) * A_noise[b * 4 + 2];
    float a11 = A_mean[3] + softplusf(A_std[3]) * A_noise[b * 4 + 3];
    float bv0 = b_mean[0] + softplusf(b_std[0]) * b_noise[b * 2 + 0];
    float bv1 = b_mean[1] + softplusf(b_std[1]) * b_noise[b * 2 + 1];
    float x0 = Xc[p * 2 + 0], x1 = Xc[p * 2 + 1];
    float xt0 = x0 * a00 + x1 * a10 + bv0;
    float xt1 = x0 * a01 + x1 * a11 + bv1;
    float proj = Wfreq[o * 2 + 0] * xt0 + Wfreq[o * 2 + 1] * xt1;
    float sv, cv;
    sincosf(proj, &sv, &cv);
    const float s = 0.08838834764831843f;   // sqrt(2/256)
    pos[(long)bp * DIM + o]       = s * cv;
    pos[(long)bp * DIM + 256 + o] = s * sv;
}

// ---------------- transpose base_pos (196,512) -> (512,196) ----------------
__global__ __launch_bounds__(256) void transpose_bp_kernel(const float* __restrict__ bp,
                                                           float* __restrict__ bpT) {
    int idx = blockIdx.x * blockDim.x + threadIdx.x;
    if (idx >= DIM * NTOK) return;
    int d = idx / NTOK, j = idx % NTOK;
    bpT[idx] = bp[(long)j * DIM + d];
}

// --------------------------- row softmax (len 196) -------------------------
__global__ __launch_bounds__(64) void softmax_kernel(float* __restrict__ attn) {
    long row = blockIdx.x;
    float* p = attn + row * NTOK;
    int t = threadIdx.x;
    float v[4];
    float mx = -INFINITY;
    #pragma unroll
    for (int j = 0; j < 4; j++) {
        int i = t + j * 64;
        v[j] = (i < NTOK) ? p[i] : -INFINITY;
        mx = fmaxf(mx, v[j]);
    }
    #pragma unroll
    for (int off = 32; off >= 1; off >>= 1) mx = fmaxf(mx, __shfl_xor(mx, off));
    float sum = 0.f;
    #pragma unroll
    for (int j = 0; j < 4; j++) {
        int i = t + j * 64;
        v[j] = (i < NTOK) ? expf(v[j] - mx) : 0.f;
        sum += v[j];
    }
    #pragma unroll
    for (int off = 32; off >= 1; off >>= 1) sum += __shfl_xor(sum, off);
    float inv = 1.0f / sum;
    #pragma unroll
    for (int j = 0; j < 4; j++) {
        int i = t + j * 64;
        if (i < NTOK) p[i] = v[j] * inv;
    }
}

// ------------------------------ LayerNorm (512) ----------------------------
__global__ __launch_bounds__(128) void ln_kernel(const float* __restrict__ x,
                                                 const float* __restrict__ g,
                                                 const float* __restrict__ bb,
                                                 float* __restrict__ out) {
    long row = blockIdx.x;
    int t = threadIdx.x;
    float4 v = *(const float4*)(x + row * DIM + t * 4);
    float s = v.x + v.y + v.z + v.w;
    float q = v.x * v.x + v.y * v.y + v.z * v.z + v.w * v.w;
    #pragma unroll
    for (int off = 32; off >= 1; off >>= 1) {
        s += __shfl_xor(s, off);
        q += __shfl_xor(q, off);
    }
    __shared__ float red[4];
    int lane = t & 63, wv = t >> 6;
    if (lane == 0) { red[wv * 2] = s; red[wv * 2 + 1] = q; }
    __syncthreads();
    float S = red[0] + red[2], Q = red[1] + red[3];
    float mean = S * (1.0f / DIM);
    float var = Q * (1.0f / DIM) - mean * mean;
    float rs = rsqrtf(var + 1e-5f);
    float4 gg = *(const float4*)(g + t * 4);
    float4 bv = *(const float4*)(bb + t * 4);
    float4 o;
    o.x = (v.x - mean) * rs * gg.x + bv.x;
    o.y = (v.y - mean) * rs * gg.y + bv.y;
    o.z = (v.z - mean) * rs * gg.z + bv.z;
    o.w = (v.w - mean) * rs * gg.w + bv.w;
    *(float4*)(out + row * DIM + t * 4) = o;
}

// ------------------------- generic guarded tile GEMM -----------------------
// C[bz] = act( A[bz] @ B[bz] * scale + bias ) (+ C residual)
// 64x64 tile, BK=16, 256 threads, 4x4 microtile.
template <bool GELU, bool RESID>
__global__ __launch_bounds__(256) void gemm_tile(const float* __restrict__ A,
                                                 const float* __restrict__ Bm,
                                                 const float* __restrict__ bias,
                                                 float* __restrict__ C,
                                                 int M, int N, int K,
                                                 int lda, int ldb, int ldc,
                                                 long bsA, long bsB, long bsC,
                                                 float scale) {
    int bz = blockIdx.z;
    A += (long)bz * bsA;
    Bm += (long)bz * bsB;
    C += (long)bz * bsC;

    int n0 = blockIdx.x * 64, m0 = blockIdx.y * 64;
    __shared__ float As[16][68];
    __shared__ float Bs[16][68];
    int tid = threadIdx.x;
    int tx = tid & 15, ty = tid >> 4;
    int ar = tid >> 2, ac = (tid & 3) * 4;     // A: row 0..63, col 0,4,8,12
    int br = tid >> 4, bc = (tid & 15) * 4;    // B: row 0..15, col 0..60

    float acc[4][4] = {};

    for (int k0 = 0; k0 < K; k0 += 16) {
        // --- load A tile (transposed into LDS) ---
        {
            float4 v = make_float4(0.f, 0.f, 0.f, 0.f);
            int row = m0 + ar;
            if (row < M) {
                if (k0 + ac + 3 < K) {
                    v = *(const float4*)(A + (long)row * lda + k0 + ac);
                } else {
                    float t0 = (k0 + ac + 0 < K) ? A[(long)row * lda + k0 + ac + 0] : 0.f;
                    float t1 = (k0 + ac + 1 < K) ? A[(long)row * lda + k0 + ac + 1] : 0.f;
                    float t2 = (k0 + ac + 2 < K) ? A[(long)row * lda + k0 + ac + 2] : 0.f;
                    float t3 = (k0 + ac + 3 < K) ? A[(long)row * lda + k0 + ac + 3] : 0.f;
                    v = make_float4(t0, t1, t2, t3);
                }
            }
            As[ac + 0][ar] = v.x;
            As[ac + 1][ar] = v.y;
            As[ac + 2][ar] = v.z;
            As[ac + 3][ar] = v.w;
        }
        // --- load B tile ---
        {
            float4 v = make_float4(0.f, 0.f, 0.f, 0.f);
            int krow = k0 + br;
            if (krow < K) {
                if (n0 + bc + 3 < N) {
                    v = *(const float4*)(Bm + (long)krow * ldb + n0 + bc);
                } else {
                    float t0 = (n0 + bc + 0 < N) ? Bm[(long)krow * ldb + n0 + bc + 0] : 0.f;
                    float t1 = (n0 + bc + 1 < N) ? Bm[(long)krow * ldb + n0 + bc + 1] : 0.f;
                    float t2 = (n0 + bc + 2 < N) ? Bm[(long)krow * ldb + n0 + bc + 2] : 0.f;
                    float t3 = (n0 + bc + 3 < N) ? Bm[(long)krow * ldb + n0 + bc + 3] : 0.f;
                    v = make_float4(t0, t1, t2, t3);
                }
            }
            *(float4*)&Bs[br][bc] = v;
        }
        __syncthreads();
        #pragma unroll
        for (int k = 0; k < 16; k++) {
            float4 a = *(const float4*)&As[k][ty * 4];
            float4 b = *(const float4*)&Bs[k][tx * 4];
            float av[4] = {a.x, a.y, a.z, a.w};
            float bv[4] = {b.x, b.y, b.z, b.w};
            #pragma unroll
            for (int i = 0; i < 4; i++)
                #pragma unroll
                for (int j = 0; j < 4; j++) acc[i][j] += av[i] * bv[j];
        }
        __syncthreads();
    }

    #pragma unroll
    for (int i = 0; i < 4; i++) {
        int row = m0 + ty * 4 + i;
        if (row >= M) continue;
        #pragma unroll
        for (int j = 0; j < 4; j++) {
            int col = n0 + tx * 4 + j;
            if (col >= N) continue;
            float v = acc[i][j] * scale;
            if (bias) v += bias[col];
            if (GELU) v = 0.5f * v * (1.0f + erff(v * 0.70710678118654752f));
            long cidx = (long)row * ldc + col;
            if (RESID) v += C[cidx];
            C[cidx] = v;
        }
    }
}

// ---------------------------------------------------------------------------

extern "C" void kernel_launch(void* const* d_in, const int* in_sizes, int n_in,
                              void* d_out, int out_size, void* d_ws, size_t ws_size,
                              hipStream_t stream) {
    const float* img      = (const float*)d_in[0];
    const float* A_noise  = (const float*)d_in[2];
    const float* b_noise  = (const float*)d_in[3];
    const float* Wfreq    = (const float*)d_in[4];
    const float* Xc       = (const float*)d_in[5];
    const float* base_pos = (const float*)d_in[6];
    const float* A_mean   = (const float*)d_in[7];
    const float* b_mean   = (const float*)d_in[8];
    const float* A_std    = (const float*)d_in[9];
    const float* b_std    = (const float*)d_in[10];
    const float* Wpe      = (const float*)d_in[11];
    const float* bpe      = (const float*)d_in[12];
    const float* Wep      = (const float*)d_in[13];
    const float* bep      = (const float*)d_in[14];
    const float* ln1_g    = (const float*)d_in[15];
    const float* ln1_b    = (const float*)d_in[16];
    const float* Wqkv     = (const float*)d_in[17];
    const float* Wout     = (const float*)d_in[18];
    const float* bout     = (const float*)d_in[19];
    const float* ln2_g    = (const float*)d_in[20];
    const float* ln2_b    = (const float*)d_in[21];
    const float* Wff1     = (const float*)d_in[22];
    const float* bff1     = (const float*)d_in[23];
    const float* Wff2     = (const float*)d_in[24];
    const float* bff2     = (const float*)d_in[25];

    float* ws = (float*)d_ws;
    const long SZ_X = (long)MROWS * DIM;           // 6,422,528 floats
    float* xb    = ws;
    float* bufA  = xb + SZ_X;
    float* bufB  = bufA + SZ_X;
    float* attn  = bufB + SZ_X;                    // 2,458,624 floats
    float* h1    = attn + (long)B_ * NTOK * NTOK;  // 25,690,112 floats
    float* bposT = h1 + (long)MROWS * MLP;         // 100,352 floats

    const float SCALE = 0.044194173824159216f;     // 512^-0.5

    // 1) patchify -> h1 (as 12544 x 768)
    {
        long tot = (long)MROWS * PDIM;
        patchify_kernel<<<dim3((tot + 255) / 256), dim3(256), 0, stream>>>(img, h1);
    }
    // 2) patch embed: h1 @ Wpe + bpe -> xb
    gemm_tile<false, false><<<dim3(8, 196, 1), dim3(256), 0, stream>>>(
        h1, Wpe, bpe, xb, MROWS, DIM, PDIM, PDIM, DIM, DIM, 0, 0, 0, 1.0f);
    // 3) transformed positional embedding -> bufA (12544 x 512)
    pos_kernel<<<dim3(MROWS), dim3(256), 0, stream>>>(
        Xc, Wfreq, A_noise, b_noise, A_mean, b_mean, A_std, b_std, bufA);
    // 4) transpose base_pos -> bposT
    transpose_bp_kernel<<<dim3((DIM * NTOK + 255) / 256), dim3(256), 0, stream>>>(
        base_pos, bposT);
    // 5) dots = pos @ base_posT * SCALE -> attn
    gemm_tile<false, false><<<dim3(4, 196, 1), dim3(256), 0, stream>>>(
        bufA, bposT, nullptr, attn, MROWS, NTOK, DIM, DIM, NTOK, NTOK, 0, 0, 0, SCALE);
    // 6) softmax rows
    softmax_kernel<<<dim3(MROWS), dim3(64), 0, stream>>>(attn);

    for (int l = 0; l < 4; l++) {
        // LN1: xb -> bufA
        ln_kernel<<<dim3(MROWS), dim3(128), 0, stream>>>(
            xb, ln1_g + l * DIM, ln1_b + l * DIM, bufA);
        // v = xn @ Wqkv[l][:,1024:1536] -> bufB  (q,k are dead)
        gemm_tile<false, false><<<dim3(8, 196, 1), dim3(256), 0, stream>>>(
            bufA, Wqkv + (long)l * DIM * 1536 + 1024, nullptr, bufB,
            MROWS, DIM, DIM, DIM, 1536, DIM, 0, 0, 0, 1.0f);
        // out = attn @ v (batched over B) -> bufA
        gemm_tile<false, false><<<dim3(8, 4, B_), dim3(256), 0, stream>>>(
            attn, bufB, nullptr, bufA, NTOK, DIM, NTOK, NTOK, DIM, DIM,
            (long)NTOK * NTOK, (long)NTOK * DIM, (long)NTOK * DIM, 1.0f);
        // x = out @ Wout[l] + bout[l] -> xb
        gemm_tile<false, false><<<dim3(8, 196, 1), dim3(256), 0, stream>>>(
            bufA, Wout + (long)l * DIM * DIM, bout + l * DIM, xb,
            MROWS, DIM, DIM, DIM, DIM, DIM, 0, 0, 0, 1.0f);
        // LN2: xb -> bufA
        ln_kernel<<<dim3(MROWS), dim3(128), 0, stream>>>(
            xb, ln2_g + l * DIM, ln2_b + l * DIM, bufA);
        // h1 = gelu(xn2 @ Wff1[l] + bff1[l])
        gemm_tile<true, false><<<dim3(32, 196, 1), dim3(256), 0, stream>>>(
            bufA, Wff1 + (long)l * DIM * MLP, bff1 + l * MLP, h1,
            MROWS, MLP, DIM, DIM, MLP, MLP, 0, 0, 0, 1.0f);
        // x = h1 @ Wff2[l] + bff2[l] + x -> xb (residual in-place)
        gemm_tile<false, true><<<dim3(8, 196, 1), dim3(256), 0, stream>>>(
            h1, Wff2 + (long)l * MLP * DIM, bff2 + l * DIM, xb,
            MROWS, DIM, MLP, MLP, DIM, DIM, 0, 0, 0, 1.0f);
    }

    // final projection: xb @ Wep + bep -> h1 (as 12544 x 768)
    gemm_tile<false, false><<<dim3(12, 196, 1), dim3(256), 0, stream>>>(
        xb, Wep, bep, h1, MROWS, PDIM, DIM, DIM, PDIM, PDIM, 0, 0, 0, 1.0f);
    // unpatchify -> d_out
    {
        long tot = (long)B_ * CCH * IMGHW * IMGHW;
        unpatchify_kernel<<<dim3((tot + 255) / 256), dim3(256), 0, stream>>>(
            h1, (float*)d_out);
    }
}

// Round 4
// 1334.311 us; speedup vs baseline: 3.4271x; 3.4271x over previous
//
#include <hip/hip_runtime.h>
#include <hip/hip_bf16.h>
#include <math.h>

// ---------------------------------------------------------------------------
// GeometricAugmentor forward — bf16 MFMA version (r3: re-audited resubmit).
//  * q,k of QKV are dead; attn computed once, shared across layers/heads.
//  * All GEMMs via mfma_f32_16x16x32_bf16, fp32 accumulate.
//  * A row-major M*K, Bt row-major N*K (weights pre-transposed on device).
//  * attn@v computed as out^T = v^T @ attn^T so both operands are natural.
//  * LN / softmax / residual stream / epilogues in fp32.
// ---------------------------------------------------------------------------

#define B_    64
#define NTOK  196
#define CCH   3
#define PDIM  768
#define DIM   512
#define MLP   2048
#define MROWS (B_ * NTOK)      // 12544
#define IMGHW 224
#define KPAD  224              // per-batch padded token count for attn@v K
#define VTLD  (B_ * KPAD)      // 14336

typedef __attribute__((ext_vector_type(8))) short bf16x8;
typedef __attribute__((ext_vector_type(4))) float f32x4;

static __device__ __forceinline__ unsigned short f2b(float f) {
    unsigned int x = __float_as_uint(f);
    unsigned int r = (x + 0x7FFFu + ((x >> 16) & 1u)) >> 16;
    return (unsigned short)r;
}
static __device__ __forceinline__ float softplusf(float x) {
    return fmaxf(x, 0.0f) + log1pf(expf(-fabsf(x)));
}

// ------------------------- patchify: img -> (M,768) bf16 -------------------
__global__ __launch_bounds__(256) void patchify_kernel(const float* __restrict__ img,
                                                       unsigned short* __restrict__ xp) {
    long idx = (long)blockIdx.x * blockDim.x + threadIdx.x;
    if (idx >= (long)MROWS * PDIM) return;
    int pd = (int)(idx % PDIM);
    long bn = idx / PDIM;
    int n = (int)(bn % NTOK);
    int b = (int)(bn / NTOK);
    int c = pd % 3;
    int p12 = pd / 3;
    int p1 = p12 >> 4, p2 = p12 & 15;
    int g1 = n / 14, g2 = n % 14;
    long src = (((long)b * CCH + c) * IMGHW + (g1 * 16 + p1)) * IMGHW + (g2 * 16 + p2);
    xp[idx] = f2b(img[src]);
}

// ---------------------- unpatchify: (M,768) f32 -> img ---------------------
__global__ __launch_bounds__(256) void unpatchify_kernel(const float* __restrict__ y,
                                                         float* __restrict__ out) {
    long idx = (long)blockIdx.x * blockDim.x + threadIdx.x;
    if (idx >= (long)B_ * CCH * IMGHW * IMGHW) return;
    int ww = (int)(idx % IMGHW);
    long r = idx / IMGHW;
    int hh = (int)(r % IMGHW);
    r /= IMGHW;
    int c = (int)(r % CCH);
    int b = (int)(r / CCH);
    int g1 = hh >> 4, p1 = hh & 15;
    int g2 = ww >> 4, p2 = ww & 15;
    int n = g1 * 14 + g2;
    int pd = (p1 * 16 + p2) * 3 + c;
    out[idx] = y[((long)b * NTOK + n) * PDIM + pd];
}

// -------- pos embedding: fused affine transform + random-Fourier (bf16) ----
__global__ __launch_bounds__(256) void pos_kernel(const float* __restrict__ Xc,
                                                  const float* __restrict__ Wfreq,
                                                  const float* __restrict__ A_noise,
                                                  const float* __restrict__ b_noise,
                                                  const float* __restrict__ A_mean,
                                                  const float* __restrict__ b_mean,
                                                  const float* __restrict__ A_std,
                                                  const float* __restrict__ b_std,
                                                  unsigned short* __restrict__ pos) {
    int bp = blockIdx.x;              // 0 .. 12543
    int b = bp / NTOK, p = bp % NTOK;
    int o = threadIdx.x;              // 0 .. 255
    float a00 = A_mean[0] + softplusf(A_std[0]) * A_noise[b * 4 + 0];
    float a01 = A_mean[1] + softplusf(A_std[1]) * A_noise[b * 4 + 1];
    float a10 = A_mean[2] + softplusf(A_std[2]) * A_noise[b * 4 + 2];
    float a11 = A_mean[3] + softplusf(A_std[3]) * A_noise[b * 4 + 3];
    float bv0 = b_mean[0] + softplusf(b_std[0]) * b_noise[b * 2 + 0];
    float bv1 = b_mean[1] + softplusf(b_std[1]) * b_noise[b * 2 + 1];
    float x0 = Xc[p * 2 + 0], x1 = Xc[p * 2 + 1];
    float xt0 = x0 * a00 + x1 * a10 + bv0;
    float xt1 = x0 * a01 + x1 * a11 + bv1;
    float proj = Wfreq[o * 2 + 0] * xt0 + Wfreq[o * 2 + 1] * xt1;
    float sv, cv;
    sincosf(proj, &sv, &cv);
    const float s = 0.08838834764831843f;   // sqrt(2/256)
    pos[(long)bp * DIM + o]       = f2b(s * cv);
    pos[(long)bp * DIM + 256 + o] = f2b(s * sv);
}

// --------------- row softmax (len 196), f32 in -> bf16 out -----------------
__global__ __launch_bounds__(64) void softmax_kernel(const float* __restrict__ dots,
                                                     unsigned short* __restrict__ attn) {
    long row = blockIdx.x;
    const float* p = dots + row * NTOK;
    unsigned short* q = attn + row * NTOK;
    int t = threadIdx.x;
    float v[4];
    float mx = -INFINITY;
    #pragma unroll
    for (int j = 0; j < 4; j++) {
        int i = t + j * 64;
        v[j] = (i < NTOK) ? p[i] : -INFINITY;
        mx = fmaxf(mx, v[j]);
    }
    #pragma unroll
    for (int off = 32; off >= 1; off >>= 1) mx = fmaxf(mx, __shfl_xor(mx, off));
    float sum = 0.f;
    #pragma unroll
    for (int j = 0; j < 4; j++) {
        int i = t + j * 64;
        v[j] = (i < NTOK) ? expf(v[j] - mx) : 0.f;
        sum += v[j];
    }
    #pragma unroll
    for (int off = 32; off >= 1; off >>= 1) sum += __shfl_xor(sum, off);
    float inv = 1.0f / sum;
    #pragma unroll
    for (int j = 0; j < 4; j++) {
        int i = t + j * 64;
        if (i < NTOK) q[i] = f2b(v[j] * inv);
    }
}

// ---------------- LayerNorm (512): f32 in -> bf16 out ----------------------
__global__ __launch_bounds__(128) void ln_kernel(const float* __restrict__ x,
                                                 const float* __restrict__ g,
                                                 const float* __restrict__ bb,
                                                 unsigned short* __restrict__ out) {
    long row = blockIdx.x;
    int t = threadIdx.x;
    float4 v = *(const float4*)(x + row * DIM + t * 4);
    float s = v.x + v.y + v.z + v.w;
    float q = v.x * v.x + v.y * v.y + v.z * v.z + v.w * v.w;
    #pragma unroll
    for (int off = 32; off >= 1; off >>= 1) {
        s += __shfl_xor(s, off);
        q += __shfl_xor(q, off);
    }
    __shared__ float red[4];
    int lane = t & 63, wv = t >> 6;
    if (lane == 0) { red[wv * 2] = s; red[wv * 2 + 1] = q; }
    __syncthreads();
    float S = red[0] + red[2], Q = red[1] + red[3];
    float mean = S * (1.0f / DIM);
    float var = Q * (1.0f / DIM) - mean * mean;
    float rs = rsqrtf(var + 1e-5f);
    float4 gg = *(const float4*)(g + t * 4);
    float4 bv = *(const float4*)(bb + t * 4);
    ushort4 o;
    o.x = f2b((v.x - mean) * rs * gg.x + bv.x);
    o.y = f2b((v.y - mean) * rs * gg.y + bv.y);
    o.z = f2b((v.z - mean) * rs * gg.z + bv.z);
    o.w = f2b((v.w - mean) * rs * gg.w + bv.w);
    *(ushort4*)(out + row * DIM + t * 4) = o;
}

// --------- fused weight transpose+convert: fp32 (R x C) -> bf16 (C x R) ----
struct TDesc {
    const float* in;
    unsigned short* out;
    int R, C, ld, cb, bbase, tx, trans;
};
struct TPack { TDesc d[19]; int n; };

__global__ __launch_bounds__(256) void wconv_kernel(TPack p) {
    __shared__ float t[32][33];
    int bid = blockIdx.x;
    int di = 0;
    for (int i = 1; i < p.n; ++i) if (bid >= p.d[i].bbase) di = i;
    TDesc d = p.d[di];
    int local = bid - d.bbase;
    int bx = local % d.tx, by = local / d.tx;
    int r0 = by * 32, c0 = bx * 32;
    int lx = threadIdx.x & 31, ly = threadIdx.x >> 5;
    if (d.trans) {
        #pragma unroll
        for (int i = 0; i < 4; i++) {
            int r = r0 + ly + i * 8, c = c0 + lx;
            t[ly + i * 8][lx] = (r < d.R && c < d.C) ? d.in[(long)r * d.ld + d.cb + c] : 0.f;
        }
        __syncthreads();
        #pragma unroll
        for (int i = 0; i < 4; i++) {
            int c = c0 + ly + i * 8, r = r0 + lx;
            if (c < d.C && r < d.R) d.out[(long)c * d.R + r] = f2b(t[lx][ly + i * 8]);
        }
    } else {
        #pragma unroll
        for (int i = 0; i < 4; i++) {
            int r = r0 + ly + i * 8, c = c0 + lx;
            if (r < d.R && c < d.C) d.out[(long)r * d.C + c] = f2b(d.in[(long)r * d.ld + d.cb + c]);
        }
    }
}

// -------- bf16 transpose: in (R x C, inld) -> out[c*outld + remap(r)] ------
// remap(r) = (r/grp)*gstride + r%grp when grp>0 (per-batch K padding), else r.
__global__ __launch_bounds__(256) void tbf16_kernel(const unsigned short* __restrict__ in,
                                                    unsigned short* __restrict__ out,
                                                    int R, int C, int inld, int outld,
                                                    int grp, int gstride) {
    __shared__ unsigned short t[32][33];
    int r0 = blockIdx.y * 32, c0 = blockIdx.x * 32;
    int lx = threadIdx.x & 31, ly = threadIdx.x >> 5;
    #pragma unroll
    for (int i = 0; i < 4; i++) {
        int r = r0 + ly + i * 8, c = c0 + lx;
        t[ly + i * 8][lx] = (r < R && c < C) ? in[(long)r * inld + c] : 0;
    }
    __syncthreads();
    #pragma unroll
    for (int i = 0; i < 4; i++) {
        int c = c0 + ly + i * 8, r = r0 + lx;
        if (c < C && r < R) {
            int oc = grp ? (r / grp) * gstride + (r % grp) : r;
            out[(long)c * outld + oc] = t[lx][ly + i * 8];
        }
    }
}

// ----------------------------- MFMA GEMM -----------------------------------
// C = act(A @ Bt^T * scale + bias) [+ residual]; A: M x K (lda), Bt: N x K (ldb).
// 128x128 tile, BK=32, 256 threads (4 waves, 2x2 of 64x64), reg-staged LDS.
// M and K must be multiples of 128 / 32; N guarded.
template <bool GELU, bool RESID, bool WF32, bool WB16>
__global__ __launch_bounds__(256) void mgemm(const unsigned short* __restrict__ A,
                                             const unsigned short* __restrict__ Bt,
                                             const float* __restrict__ bias,
                                             const float* __restrict__ Rsd,
                                             float* __restrict__ Cf,
                                             unsigned short* __restrict__ Cb,
                                             int M, int N, int K,
                                             int lda, int ldb, int ldc,
                                             long bsA, long bsBt, long bsC,
                                             float scale) {
    int bz = blockIdx.z;
    A  += bz * bsA;
    Bt += bz * bsBt;
    __shared__ __attribute__((aligned(16))) unsigned short As[128][40];
    __shared__ __attribute__((aligned(16))) unsigned short Bs[128][40];
    int m0 = blockIdx.y * 128, n0 = blockIdx.x * 128;
    int tid = threadIdx.x;
    int wave = tid >> 6, lane = tid & 63;
    int wm = (wave & 1) * 64, wn = (wave >> 1) * 64;
    int fr = lane & 15, fg = lane >> 4;
    int ar = tid >> 1, ah = tid & 1;      // staging: row, k-half

    f32x4 acc[4][4];
    #pragma unroll
    for (int i = 0; i < 4; i++)
        #pragma unroll
        for (int j = 0; j < 4; j++) acc[i][j] = (f32x4)0.f;

    int brow = n0 + ar; if (brow >= N) brow = N - 1;   // clamp (pad tiles)
    const unsigned short* pa0 = A + (long)(m0 + ar) * lda + ah * 16;
    const unsigned short* pb0 = Bt + (long)brow * ldb + ah * 16;

    for (int k0 = 0; k0 < K; k0 += 32) {
        bf16x8 a0 = *(const bf16x8*)(pa0 + k0);
        bf16x8 a1 = *(const bf16x8*)(pa0 + k0 + 8);
        bf16x8 b0 = *(const bf16x8*)(pb0 + k0);
        bf16x8 b1 = *(const bf16x8*)(pb0 + k0 + 8);
        __syncthreads();
        *(bf16x8*)&As[ar][ah * 16]     = a0;
        *(bf16x8*)&As[ar][ah * 16 + 8] = a1;
        *(bf16x8*)&Bs[ar][ah * 16]     = b0;
        *(bf16x8*)&Bs[ar][ah * 16 + 8] = b1;
        __syncthreads();
        bf16x8 af[4], bfr[4];
        #pragma unroll
        for (int i = 0; i < 4; i++) af[i]  = *(const bf16x8*)&As[wm + i * 16 + fr][fg * 8];
        #pragma unroll
        for (int j = 0; j < 4; j++) bfr[j] = *(const bf16x8*)&Bs[wn + j * 16 + fr][fg * 8];
        #pragma unroll
        for (int i = 0; i < 4; i++)
            #pragma unroll
            for (int j = 0; j < 4; j++)
                acc[i][j] = __builtin_amdgcn_mfma_f32_16x16x32_bf16(af[i], bfr[j], acc[i][j], 0, 0, 0);
    }

    long cbase = (long)bz * bsC;
    #pragma unroll
    for (int i = 0; i < 4; i++) {
        int row = m0 + wm + i * 16 + fg * 4;
        #pragma unroll
        for (int j = 0; j < 4; j++) {
            int col = n0 + wn + j * 16 + fr;
            if (col >= N) continue;
            float bv = bias ? bias[col] : 0.f;
            #pragma unroll
            for (int r = 0; r < 4; r++) {
                float v = acc[i][j][r] * scale + bv;
                if (GELU) v = 0.5f * v * (1.0f + erff(v * 0.70710678118654752f));
                long ci = cbase + (long)(row + r) * ldc + col;
                if (RESID) v += Rsd[ci];
                if (WF32) Cf[ci] = v;
                if (WB16) Cb[ci] = f2b(v);
            }
        }
    }
}

// ---------------------------------------------------------------------------

extern "C" void kernel_launch(void* const* d_in, const int* in_sizes, int n_in,
                              void* d_out, int out_size, void* d_ws, size_t ws_size,
                              hipStream_t stream) {
    const float* img      = (const float*)d_in[0];
    const float* A_noise  = (const float*)d_in[2];
    const float* b_noise  = (const float*)d_in[3];
    const float* Wfreq    = (const float*)d_in[4];
    const float* Xc       = (const float*)d_in[5];
    const float* base_pos = (const float*)d_in[6];
    const float* A_mean   = (const float*)d_in[7];
    const float* b_mean   = (const float*)d_in[8];
    const float* A_std    = (const float*)d_in[9];
    const float* b_std    = (const float*)d_in[10];
    const float* Wpe      = (const float*)d_in[11];
    const float* bpe      = (const float*)d_in[12];
    const float* Wep      = (const float*)d_in[13];
    const float* bep      = (const float*)d_in[14];
    const float* ln1_g    = (const float*)d_in[15];
    const float* ln1_b    = (const float*)d_in[16];
    const float* Wqkv     = (const float*)d_in[17];
    const float* Wout     = (const float*)d_in[18];
    const float* bout     = (const float*)d_in[19];
    const float* ln2_g    = (const float*)d_in[20];
    const float* ln2_b    = (const float*)d_in[21];
    const float* Wff1     = (const float*)d_in[22];
    const float* bff1     = (const float*)d_in[23];
    const float* Wff2     = (const float*)d_in[24];
    const float* bff2     = (const float*)d_in[25];

    char* ws = (char*)d_ws;
    // ---- workspace layout (bytes) ----
    float*          x_f    = (float*)(ws + 0);                       // 12544x512 f32
    unsigned short* sb0    = (unsigned short*)(ws + 25690112);       // xn16 / out16
    unsigned short* attn16 = (unsigned short*)(ws + 38535168);       // 64x196x196 (+slack)
    unsigned short* v16    = (unsigned short*)(ws + 43452928);       // 12544x512
    unsigned short* vT     = (unsigned short*)(ws + 56297984);       // 512x14336 (K-padded)
    unsigned short* outT   = (unsigned short*)(ws + 70978048);       // 512x12544 ; also xb16
    unsigned short* h1     = (unsigned short*)(ws + 83823104);       // 12544x2048 -> ends 135203328
    // carved from h1 region (dead before first FF1):
    unsigned short* pat16  = (unsigned short*)(ws + 83823104);                // 12544x768
    unsigned short* pos16  = (unsigned short*)(ws + 83823104 + 19267584);     // 12544x512
    float*          dots   = (float*)(ws + 83823104 + 19267584 + 12845056);   // 12544x196 f32
    float*          y_f    = (float*)(ws + 83823104);                // 12544x768 f32 (after h1 dead)
    // weights (bf16, transposed to N x K) — placed AFTER h1 end
    char* wp = ws + 135203328;
    unsigned short* WpeT   = (unsigned short*)(wp);                  // 512x768
    unsigned short* WqkvT  = (unsigned short*)(wp + 786432);         // 4 x 512x512 (V slice)
    unsigned short* WoutT  = (unsigned short*)(wp + 786432 + 2097152);
    unsigned short* Wff1T  = (unsigned short*)(wp + 786432 + 2 * 2097152);    // 4 x 2048x512
    unsigned short* Wff2T  = (unsigned short*)(wp + 786432 + 2 * 2097152 + 8388608); // 4 x 512x2048
    unsigned short* WepT   = (unsigned short*)(wp + 786432 + 2 * 2097152 + 2 * 8388608); // 768x512
    unsigned short* bp16   = (unsigned short*)(wp + 2 * 786432 + 2 * 2097152 + 2 * 8388608); // 196x512
    // end of workspace use: 135203328 + 22745088 = 157948416 bytes (~151 MiB)

    const float SCALE = 0.044194173824159216f;     // 512^-0.5

    // 0) zero vT (its per-batch K-padding columns must be exactly 0)
    hipMemsetAsync(vT, 0, (size_t)512 * VTLD * 2, stream);

    // 0b) weight conversion / transposition, one fused kernel
    {
        TPack p; int bb = 0, di = 0;
        auto add = [&](const float* in, unsigned short* out, int R, int C, int ld, int cb, int tr) {
            TDesc d; d.in = in; d.out = out; d.R = R; d.C = C; d.ld = ld; d.cb = cb;
            d.trans = tr; d.tx = (C + 31) / 32; d.bbase = bb;
            bb += d.tx * ((R + 31) / 32);
            p.d[di++] = d;
        };
        add(Wpe, WpeT, 768, 512, 512, 0, 1);
        for (int l = 0; l < 4; l++) add(Wqkv + (long)l * 512 * 1536, WqkvT + (long)l * 512 * 512, 512, 512, 1536, 1024, 1);
        for (int l = 0; l < 4; l++) add(Wout + (long)l * 512 * 512, WoutT + (long)l * 512 * 512, 512, 512, 512, 0, 1);
        for (int l = 0; l < 4; l++) add(Wff1 + (long)l * 512 * 2048, Wff1T + (long)l * 2048 * 512, 512, 2048, 2048, 0, 1);
        for (int l = 0; l < 4; l++) add(Wff2 + (long)l * 2048 * 512, Wff2T + (long)l * 512 * 2048, 2048, 512, 512, 0, 1);
        add(Wep, WepT, 512, 768, 768, 0, 1);
        add(base_pos, bp16, 196, 512, 512, 0, 0);
        p.n = di;
        wconv_kernel<<<dim3(bb), dim3(256), 0, stream>>>(p);
    }

    // 1) patchify -> pat16
    patchify_kernel<<<dim3((MROWS * PDIM + 255) / 256), dim3(256), 0, stream>>>(img, pat16);
    // 2) patch embed: pat16 @ WpeT^T + bpe -> x_f
    mgemm<false, false, true, false><<<dim3(4, 98), dim3(256), 0, stream>>>(
        pat16, WpeT, bpe, nullptr, x_f, nullptr, MROWS, DIM, PDIM, PDIM, PDIM, DIM, 0, 0, 0, 1.0f);
    // 3) positional embedding -> pos16
    pos_kernel<<<dim3(MROWS), dim3(256), 0, stream>>>(
        Xc, Wfreq, A_noise, b_noise, A_mean, b_mean, A_std, b_std, pos16);
    // 4) dots = pos @ base_pos^T * SCALE -> dots (f32)
    mgemm<false, false, true, false><<<dim3(2, 98), dim3(256), 0, stream>>>(
        pos16, bp16, nullptr, nullptr, dots, nullptr, MROWS, NTOK, DIM, DIM, DIM, NTOK, 0, 0, 0, SCALE);
    // 5) softmax -> attn16 (bf16)
    softmax_kernel<<<dim3(MROWS), dim3(64), 0, stream>>>(dots, attn16);

    for (int l = 0; l < 4; l++) {
        // LN1: x_f -> sb0
        ln_kernel<<<dim3(MROWS), dim3(128), 0, stream>>>(x_f, ln1_g + l * DIM, ln1_b + l * DIM, sb0);
        // v = xn @ Wv^T -> v16
        mgemm<false, false, false, true><<<dim3(4, 98), dim3(256), 0, stream>>>(
            sb0, WqkvT + (long)l * 512 * 512, nullptr, nullptr, nullptr, v16,
            MROWS, DIM, DIM, DIM, DIM, DIM, 0, 0, 0, 1.0f);
        // v -> vT (512 x 14336, per-batch 224-wide with zero pad)
        tbf16_kernel<<<dim3(16, 392), dim3(256), 0, stream>>>(v16, vT, MROWS, DIM, DIM, VTLD, NTOK, KPAD);
        // outT_b = vT_b @ attn_b^T   (M=512, N=196, K=224)
        mgemm<false, false, false, true><<<dim3(2, 4, B_), dim3(256), 0, stream>>>(
            vT, attn16, nullptr, nullptr, nullptr, outT,
            512, NTOK, KPAD, VTLD, NTOK, MROWS, KPAD, (long)NTOK * NTOK, NTOK, 1.0f);
        // outT -> out16 (sb0)
        tbf16_kernel<<<dim3(392, 16), dim3(256), 0, stream>>>(outT, sb0, DIM, MROWS, MROWS, DIM, 0, 0);
        // x = out @ Wout^T + bout -> x_f
        mgemm<false, false, true, false><<<dim3(4, 98), dim3(256), 0, stream>>>(
            sb0, WoutT + (long)l * 512 * 512, bout + l * DIM, nullptr, x_f, nullptr,
            MROWS, DIM, DIM, DIM, DIM, DIM, 0, 0, 0, 1.0f);
        // LN2: x_f -> sb0
        ln_kernel<<<dim3(MROWS), dim3(128), 0, stream>>>(x_f, ln2_g + l * DIM, ln2_b + l * DIM, sb0);
        // h1 = gelu(xn2 @ Wff1^T + bff1) (bf16)
        mgemm<true, false, false, true><<<dim3(16, 98), dim3(256), 0, stream>>>(
            sb0, Wff1T + (long)l * 2048 * 512, bff1 + l * MLP, nullptr, nullptr, h1,
            MROWS, MLP, DIM, DIM, DIM, MLP, 0, 0, 0, 1.0f);
        // x = h1 @ Wff2^T + bff2 + x  (dual write: x_f f32 + xb16 bf16)
        mgemm<false, true, true, true><<<dim3(4, 98), dim3(256), 0, stream>>>(
            h1, Wff2T + (long)l * 512 * 2048, bff2 + l * DIM, x_f, x_f, outT,
            MROWS, DIM, MLP, MLP, MLP, DIM, 0, 0, 0, 1.0f);
    }

    // final projection: xb16 @ Wep^T + bep -> y_f
    mgemm<false, false, true, false><<<dim3(6, 98), dim3(256), 0, stream>>>(
        outT, WepT, bep, nullptr, y_f, nullptr, MROWS, PDIM, DIM, DIM, DIM, PDIM, 0, 0, 0, 1.0f);
    // unpatchify -> d_out
    unpatchify_kernel<<<dim3(((long)B_ * CCH * IMGHW * IMGHW + 255) / 256), dim3(256), 0, stream>>>(
        y_f, (float*)d_out);
}